// Round 1
// baseline (219.888 us; speedup 1.0000x reference)
//
#include <hip/hip_runtime.h>
#include <math.h>

#define BATCH 256
#define FB    64
#define NCOL  147456   // 128*128*3*3
#define TPB   256
#define BT    32       // batch tile per block

#define FMA4(a, s, w) do { \
    (a).x = fmaf((s), (w).x, (a).x); \
    (a).y = fmaf((s), (w).y, (a).y); \
    (a).z = fmaf((s), (w).z, (a).z); \
    (a).w = fmaf((s), (w).w, (a).w); \
} while (0)

// Fused: per-block softmax over its 32 batch rows + bank-weighted GEMM.
// out[b][n] = sum_f softmax(x)[b][f] * W[f][n]
// Block: 256 threads x 4 cols (float4) = 1024 cols, 32-batch tile.
// Grid: (NCOL/1024, BATCH/BT) = (144, 8).
__global__ __launch_bounds__(TPB, 2) void bank_gemm_fused(
        const float* __restrict__ W, const float* __restrict__ X,
        float* __restrict__ out) {
    __shared__ float pt[FB * BT];   // pt[f*BT + b]  (transposed probs tile)

    const int tid = threadIdx.x;
    const int bg  = blockIdx.y;
    const int ncol4 = NCOL / 4;
    const float4* Wv = (const float4*)W;
    const int c4 = blockIdx.x * TPB + tid;   // this thread's float4 column

    // Issue the f=0 weight load BEFORE the softmax prologue: its ~500cy HBM
    // latency hides under the shuffle-reduce work below.
    float4 w = Wv[c4];

    // Fused softmax. FB == wave width (64): one row per wave pass, shfl-xor
    // butterfly for max and sum. Wave i handles rows i, i+4, ..., i+28.
    // Redundant across the 144 column-blocks but only 8 KB of L2-hit reads.
    const int wave = tid >> 6;
    const int lane = tid & 63;
#pragma unroll
    for (int r0 = 0; r0 < BT / 4; ++r0) {
        const int r = r0 * 4 + wave;
        float v = X[(bg * BT + r) * FB + lane];
        float m = v;
#pragma unroll
        for (int o = 32; o > 0; o >>= 1) m = fmaxf(m, __shfl_xor(m, o));
        float e = __expf(v - m);
        float s = e;
#pragma unroll
        for (int o = 32; o > 0; o >>= 1) s += __shfl_xor(s, o);
        // Transposed store (f = lane, b = r). 64-way bank conflict on these 8
        // writes/wave is a one-off ~hundreds of cycles: negligible vs main loop,
        // and padding would break the float4-aligned broadcast reads below.
        pt[lane * BT + r] = e / s;
    }
    __syncthreads();

    float4 acc[BT];
#pragma unroll
    for (int b = 0; b < BT; ++b) acc[b] = make_float4(0.f, 0.f, 0.f, 0.f);

    // Main K loop with one-ahead weight prefetch.
    for (int f = 0; f < FB; ++f) {
        float4 wn = w;
        if (f + 1 < FB) wn = Wv[(f + 1) * ncol4 + c4];
        const float4* p4 = (const float4*)&pt[f * BT];
#pragma unroll
        for (int q = 0; q < BT / 4; ++q) {
            const float4 p = p4[q];   // uniform-address LDS broadcast
            FMA4(acc[4 * q + 0], p.x, w);
            FMA4(acc[4 * q + 1], p.y, w);
            FMA4(acc[4 * q + 2], p.z, w);
            FMA4(acc[4 * q + 3], p.w, w);
        }
        w = wn;
    }

    // Coalesced float4 stores.
    float4* Ov = (float4*)out;
    const long long obase = (long long)(bg * BT) * ncol4 + c4;
#pragma unroll
    for (int b = 0; b < BT; ++b) {
        Ov[obase + (long long)b * ncol4] = acc[b];
    }
}

extern "C" void kernel_launch(void* const* d_in, const int* in_sizes, int n_in,
                              void* d_out, int out_size, void* d_ws, size_t ws_size,
                              hipStream_t stream) {
    const float* bank   = (const float*)d_in[0];   // (256, 64)
    const float* weight = (const float*)d_in[1];   // (64, 128,128,3,3)
    float* out   = (float*)d_out;                  // (256, 147456)
    (void)d_ws; (void)ws_size;                     // workspace no longer needed

    dim3 grid(NCOL / (TPB * 4), BATCH / BT);
    bank_gemm_fused<<<grid, TPB, 0, stream>>>(weight, bank, out);
}